// Round 15
// baseline (134.581 us; speedup 1.0000x reference)
//
#include <hip/hip_runtime.h>
#include <hip/hip_bf16.h>

#define N_ROWS 300000
#define FIN    128
#define HDIM   64
#define ODIM   32
#define KREL   5
#define BRT    256                                // rows per tile (8 waves x 32)
#define NTT    ((N_ROWS + BRT - 1) / BRT)         // 1172 tiles (last partial: 224)
#define TPB    2
#define NCHUNK ((NTT + TPB - 1) / TPB)            // 586

typedef __attribute__((ext_vector_type(8))) short bf8_t;   // 8 bf16 = 4 VGPR
typedef __attribute__((ext_vector_type(4))) float f32x4;
typedef __attribute__((ext_vector_type(4))) unsigned int u32x4;

static __device__ __forceinline__ unsigned pk2(float lo, float hi) {
  __hip_bfloat162 h = __float22bfloat162_rn(make_float2(lo, hi));
  return *reinterpret_cast<unsigned*>(&h);
}

static __device__ __forceinline__ bf8_t cvt8(float4 a, float4 b) {
  u32x4 u;
  u.x = pk2(a.x, a.y);
  u.y = pk2(a.z, a.w);
  u.z = pk2(b.x, b.y);
  u.w = pk2(b.z, b.w);
  return __builtin_bit_cast(bf8_t, u);
}

static __device__ __forceinline__ void stbf4_pk(void* base, int byte, float4 v) {
  unsigned long long p = (unsigned long long)pk2(v.x, v.y)
                       | ((unsigned long long)pk2(v.z, v.w) << 32);
  *(unsigned long long*)((char*)base + byte) = p;
}

static __device__ __forceinline__ bf8_t lds_load16(const void* base, int byte) {
  return *(const bf8_t*)((const char*)base + byte);
}

// ---------------- single fused streaming kernel ----------------
// One block = one side x TPB tiles of 256 CONTIGUOUS rows. 512 threads =
// 8 waves, each owns 32 rows (two 16-row halves). Per-row relation handled
// by masked-A MFMA; each W-fragment ds_read feeds BOTH row-halves (2 MFMAs)
// -> B-side LDS reads per row halve vs R14 (the measured bottleneck).
// Wave-private X region, issue-early/write-late, same-wave in-order DS
// hazards; no in-loop barrier. No sort/gather/scatter: fully streaming.
// LDS: 80KB W + 64KB X + 1.25KB bias ~= 145KB -> 1 block/CU (8 waves).

__global__ __launch_bounds__(512, 1) void gcn_main(
    const float* __restrict__ user, const float* __restrict__ item,
    const int* __restrict__ r, const float* __restrict__ c,
    const float* __restrict__ Wu, const float* __restrict__ bu,
    const float* __restrict__ Wv, const float* __restrict__ bv,
    const float* __restrict__ Wl, const float* __restrict__ bl,
    float* __restrict__ out)
{
  __shared__ __align__(16) unsigned short sW[KREL * HDIM * FIN];  // 80 KB bf16, swizzled
  __shared__ __align__(16) unsigned short sX[BRT * FIN];          // 64 KB bf16, swizzled
  __shared__ float sB[KREL * HDIM];                               // 1.25 KB

  const int tid   = threadIdx.x;
  const int side  = blockIdx.x & 1;           // 0: item->u_out, 1: user->v_out
  const int chunk = blockIdx.x >> 1;
  const int t_begin = chunk * TPB;
  if (t_begin >= NTT) return;
  const int t_end = (t_begin + TPB < NTT) ? t_begin + TPB : NTT;

  const float* X  = side ? user : item;
  const float* Wk = side ? Wv : Wu;
  const float* bk = side ? bv : bu;

  const int lane = tid & 63;
  const int wid  = tid >> 6;        // wave 0..7; owns tile rows [wid*32, wid*32+32)
  const int lrow = lane & 15;
  const int lkg  = lane >> 4;
  const int sh   = lane >> 5;       // staging: which row of the lane's pair
  const int c4   = lane & 31;       // staging: float4 column

  // stage ALL 5 relation weights -> bf16 LDS, XOR-swizzled (16KB per relation)
  {
    const float4* w4 = (const float4*)Wk;     // [5][64][128] f32 contiguous
    #pragma unroll
    for (int j = 0; j < 20; ++j) {
      int f4   = j * 512 + tid;               // 0..10239
      int k    = f4 >> 11;                    // 2048 float4 per relation
      int rowk = (f4 >> 5) & 63;
      int cc   = f4 & 31;
      int byte = (k << 14) + ((rowk * 256 + cc * 8) ^ ((rowk & 7) << 4));
      stbf4_pk(sW, byte, w4[f4]);
    }
  }
  if (tid < KREL * HDIM) sB[tid] = bk[tid];

  // layer-2 weights + biases in registers
  bf8_t wl[2][2];
  #pragma unroll
  for (int n2 = 0; n2 < 2; ++n2)
    #pragma unroll
    for (int k2 = 0; k2 < 2; ++k2) {
      const float* p = Wl + (size_t)(n2 * 16 + lrow) * HDIM + k2 * 32 + lkg * 8;
      wl[n2][k2] = cvt8(*(const float4*)p, *(const float4*)(p + 4));
    }
  const float blv0 = bl[lrow];
  const float blv1 = bl[16 + lrow];

  char* myX = (char*)sX + wid * 8192;   // this wave's private 32-row region
  const int rowb_off = wid * 32;

  // prologue: stage first tile's 32 rows (contiguous, clamped at N)
  #pragma unroll
  for (int it = 0; it < 16; ++it) {
    int grow = t_begin * BRT + rowb_off + it * 2 + sh;
    grow = (grow < N_ROWS) ? grow : N_ROWS - 1;
    float4 a = *(const float4*)(X + (size_t)grow * FIN + c4 * 4);
    int rl   = it * 2 + sh;
    int byte = (rl * 256 + c4 * 8) ^ ((rl & 7) << 4);
    stbf4_pk(myX, byte, a);
  }
  __syncthreads();   // sW/sB visible; ONLY barrier in the kernel

  for (int t = t_begin; t < t_end; ++t) {
    const int tile0 = t * BRT;
    const bool do_stage = (t + 1 < t_end);
    const int base = tile0 + rowb_off;

    // A-row relations for this lane's two row-halves
    int ra0 = base + lrow;        ra0 = (ra0 < N_ROWS) ? ra0 : N_ROWS - 1;
    int ra1 = base + 16 + lrow;   ra1 = (ra1 < N_ROWS) ? ra1 : N_ROWS - 1;
    const int myrel0 = r[ra0];
    const int myrel1 = r[ra1];

    // issue-early: streaming loads of tile t+1's 32 rows (write-late below)
    float4 ld[16];
    if (do_stage) {
      #pragma unroll
      for (int it = 0; it < 16; ++it) {
        int grow = base + BRT + it * 2 + sh;
        grow = (grow < N_ROWS) ? grow : N_ROWS - 1;
        ld[it] = *(const float4*)(X + (size_t)grow * FIN + c4 * 4);
      }
    }

    // epilogue inputs for both halves (natural order; clamped)
    int rQ[2][4]; float cQ[2][4];
    #pragma unroll
    for (int h = 0; h < 2; ++h) {
      #pragma unroll
      for (int q = 0; q < 4; ++q) {
        int rc = base + h * 16 + lkg * 4 + q;
        rc = (rc < N_ROWS) ? rc : N_ROWS - 1;
        rQ[h][q] = r[rc];
        cQ[h][q] = c[rc];
      }
    }

    __builtin_amdgcn_sched_barrier(0);   // pin: loads above, compute below

    // layer 1: 5-relation masked accumulation, K = 128; one B-read -> 2 MFMAs
    f32x4 acc0[4], acc1[4];
    #pragma unroll
    for (int n = 0; n < 4; ++n) {
      acc0[n] = f32x4{0.f, 0.f, 0.f, 0.f};
      acc1[n] = f32x4{0.f, 0.f, 0.f, 0.f};
    }

    const bf8_t zero8 = {};
    const int axor = (lrow & 7) << 4;   // (h*16+lrow)&7 == lrow&7 for both halves
    #pragma unroll
    for (int kc = 0; kc < 4; ++kc) {
      const int kb = (kc * 32 + lkg * 8) * 2;
      bf8_t au0 = lds_load16(myX, ((lrow)      * 256 + kb) ^ axor);
      bf8_t au1 = lds_load16(myX, ((16 + lrow) * 256 + kb) ^ axor);
      #pragma unroll
      for (int k = 0; k < KREL; ++k) {
        bf8_t a0 = (myrel0 == k) ? au0 : zero8;
        bf8_t a1 = (myrel1 == k) ? au1 : zero8;
        const int kofs = k << 14;
        #pragma unroll
        for (int n = 0; n < 4; ++n) {
          int brow = n * 16 + lrow;
          int bx   = kofs + ((brow * 256 + kb) ^ ((brow & 7) << 4));
          bf8_t w = lds_load16(sW, bx);
          acc0[n] = __builtin_amdgcn_mfma_f32_16x16x32_bf16(a0, w, acc0[n], 0, 0, 0);
          acc1[n] = __builtin_amdgcn_mfma_f32_16x16x32_bf16(a1, w, acc1[n], 0, 0, 0);
        }
      }
    }

    // epilogue 1: H = relu(c*(acc + b[rel])) -> bf16 into this wave's region
    #pragma unroll
    for (int n = 0; n < 4; ++n) {
      int hcol = n * 16 + lrow;
      #pragma unroll
      for (int q = 0; q < 4; ++q) {
        {
          int rr   = lkg * 4 + q;      // local row 0..15
          int byte = (rr * 128 + hcol * 2) ^ ((rr & 7) << 4);
          float bb = sB[rQ[0][q] * HDIM + hcol];
          float hv = fmaxf(cQ[0][q] * (acc0[n][q] + bb), 0.f);
          *(unsigned short*)(myX + byte) = (unsigned short)(pk2(hv, hv) & 0xFFFFu);
        }
        {
          int rr   = 16 + lkg * 4 + q; // local row 16..31
          int byte = (rr * 128 + hcol * 2) ^ ((rr & 7) << 4);
          float bb = sB[rQ[1][q] * HDIM + hcol];
          float hv = fmaxf(cQ[1][q] * (acc1[n][q] + bb), 0.f);
          *(unsigned short*)(myX + byte) = (unsigned short)(pk2(hv, hv) & 0xFFFFu);
        }
      }
    }

    // layer 2: two 16-row halves x [32 o], K = 64 (same-wave LDS RAW)
    f32x4 acc2_0[2], acc2_1[2];
    #pragma unroll
    for (int n2 = 0; n2 < 2; ++n2) {
      acc2_0[n2] = f32x4{0.f, 0.f, 0.f, 0.f};
      acc2_1[n2] = f32x4{0.f, 0.f, 0.f, 0.f};
    }
    #pragma unroll
    for (int k2 = 0; k2 < 2; ++k2) {
      const int kb = (k2 * 32 + lkg * 8) * 2;
      bf8_t a20 = lds_load16(myX, ((lrow)      * 128 + kb) ^ axor);
      bf8_t a21 = lds_load16(myX, ((16 + lrow) * 128 + kb) ^ axor);
      #pragma unroll
      for (int n2 = 0; n2 < 2; ++n2) {
        acc2_0[n2] = __builtin_amdgcn_mfma_f32_16x16x32_bf16(a20, wl[n2][k2], acc2_0[n2], 0, 0, 0);
        acc2_1[n2] = __builtin_amdgcn_mfma_f32_16x16x32_bf16(a21, wl[n2][k2], acc2_1[n2], 0, 0, 0);
      }
    }

    // epilogue 2: out = relu(acc2 + bl), NATURAL-ORDER coalesced stores
    const size_t obase = (size_t)side * N_ROWS * ODIM;
    #pragma unroll
    for (int n2 = 0; n2 < 2; ++n2) {
      int col  = n2 * 16 + lrow;
      float bb = (n2 == 0) ? blv0 : blv1;
      #pragma unroll
      for (int q = 0; q < 4; ++q) {
        int row0 = base + lkg * 4 + q;
        int row1 = base + 16 + lkg * 4 + q;
        if (row0 < N_ROWS)
          out[obase + (size_t)row0 * ODIM + col] = fmaxf(acc2_0[n2][q] + bb, 0.f);
        if (row1 < N_ROWS)
          out[obase + (size_t)row1 * ODIM + col] = fmaxf(acc2_1[n2][q] + bb, 0.f);
      }
    }

    __builtin_amdgcn_sched_barrier(0);   // pin: staged writes stay below compute

    // write-late: convert + ds_write tile t+1 into the SAME wave-private region
    if (do_stage) {
      #pragma unroll
      for (int it = 0; it < 16; ++it) {
        int rl   = it * 2 + sh;
        int byte = (rl * 256 + c4 * 8) ^ ((rl & 7) << 4);
        stbf4_pk(myX, byte, ld[it]);
      }
    }
  }
}

extern "C" void kernel_launch(void* const* d_in, const int* in_sizes, int n_in,
                              void* d_out, int out_size, void* d_ws, size_t ws_size,
                              hipStream_t stream) {
  const float* user = (const float*)d_in[0];
  const float* item = (const float*)d_in[1];
  const int*   r    = (const int*)d_in[2];
  const float* c    = (const float*)d_in[3];
  const float* Wu   = (const float*)d_in[4];
  const float* bu   = (const float*)d_in[5];
  const float* Wv   = (const float*)d_in[6];
  const float* bv   = (const float*)d_in[7];
  const float* Wl   = (const float*)d_in[8];
  const float* bl   = (const float*)d_in[9];
  float* out = (float*)d_out;

  gcn_main<<<2 * NCHUNK, 512, 0, stream>>>(user, item, r, c, Wu, bu, Wv, bv,
                                           Wl, bl, out);
}

// Round 16
// 99.317 us; speedup vs baseline: 1.3551x; 1.3551x over previous
//
#include <hip/hip_runtime.h>
#include <hip/hip_bf16.h>

#define N_ROWS 300000
#define FIN    128
#define HDIM   64
#define ODIM   32
#define KREL   5
#define BRT    128                                // rows per tile (8 waves x 16)
#define NTT    ((N_ROWS + BRT - 1) / BRT)         // 2344 tiles (last partial: 96 rows)
#define TPB    4
#define NCHUNK ((NTT + TPB - 1) / TPB)            // 586 (exact: 586*4 = 2344)

typedef __attribute__((ext_vector_type(8))) short bf8_t;   // 8 bf16 = 4 VGPR
typedef __attribute__((ext_vector_type(4))) float f32x4;
typedef __attribute__((ext_vector_type(4))) unsigned int u32x4;

static __device__ __forceinline__ unsigned pk2(float lo, float hi) {
  __hip_bfloat162 h = __float22bfloat162_rn(make_float2(lo, hi));
  return *reinterpret_cast<unsigned*>(&h);
}

static __device__ __forceinline__ bf8_t cvt8(float4 a, float4 b) {
  u32x4 u;
  u.x = pk2(a.x, a.y);
  u.y = pk2(a.z, a.w);
  u.z = pk2(b.x, b.y);
  u.w = pk2(b.z, b.w);
  return __builtin_bit_cast(bf8_t, u);
}

static __device__ __forceinline__ void stbf4_pk(void* base, int byte, float4 v) {
  unsigned long long p = (unsigned long long)pk2(v.x, v.y)
                       | ((unsigned long long)pk2(v.z, v.w) << 32);
  *(unsigned long long*)((char*)base + byte) = p;
}

static __device__ __forceinline__ bf8_t lds_load16(const void* base, int byte) {
  return *(const bf8_t*)((const char*)base + byte);
}

// ---------------- single fused streaming kernel + tile-local sort ----------------
// One block = one side x TPB tiles of 128 CONTIGUOUS rows. 512 threads = 8
// waves x 16 rows. PROLOGUE: counting-sort each tile's 128 rows by relation
// (2KB LDS, 4 barriers total) so same-relation rows land in the same wave ->
// the relation loop becomes wave-uniform skippable: avg 1.5 of 5 iterations
// execute (<=4 boundary waves per tile see 2 relations). Steady loop has ZERO
// barriers (wave-private X region, issue-early/write-late, same-wave in-order
// DS hazards). X loads gather only within a 128-row window (sequential at HBM
// granularity); stores scatter within the same window.
// LDS: 80KB W + 32KB X + 1.25KB bias + ~4.2KB sort ~= 118KB -> 1 block/CU.

__global__ __launch_bounds__(512, 1) void gcn_main(
    const float* __restrict__ user, const float* __restrict__ item,
    const int* __restrict__ r, const float* __restrict__ c,
    const float* __restrict__ Wu, const float* __restrict__ bu,
    const float* __restrict__ Wv, const float* __restrict__ bv,
    const float* __restrict__ Wl, const float* __restrict__ bl,
    float* __restrict__ out)
{
  __shared__ __align__(16) unsigned short sW[KREL * HDIM * FIN];  // 80 KB bf16, swizzled
  __shared__ __align__(16) unsigned short sX[BRT * FIN];          // 32 KB bf16, swizzled
  __shared__ float sB[KREL * HDIM];                               // 1.25 KB
  __shared__ int sSrc[TPB][BRT];                                  // 2 KB: sorted slot -> local row
  __shared__ int sRel[TPB][BRT];                                  // 2 KB: sorted slot -> relation
  __shared__ int sCnt[TPB][KREL];

  const int tid   = threadIdx.x;
  const int side  = blockIdx.x & 1;           // 0: item->u_out, 1: user->v_out
  const int chunk = blockIdx.x >> 1;
  const int t_begin = chunk * TPB;
  if (t_begin >= NTT) return;
  const int t_end = (t_begin + TPB < NTT) ? t_begin + TPB : NTT;

  const float* X  = side ? user : item;
  const float* Wk = side ? Wv : Wu;
  const float* bk = side ? bv : bu;

  const int lane = tid & 63;
  const int wid  = tid >> 6;        // wave 0..7; owns sorted slots [wid*16, wid*16+16)
  const int lrow = lane & 15;
  const int lkg  = lane >> 4;
  const int sh   = lane >> 5;       // staging: which row of the lane's pair
  const int c4   = lane & 31;       // staging: float4 column

  // ---- prologue A: tile-local counting sort (all TPB tiles at once) ----
  {
    const int j = tid >> 7;                 // tile 0..3
    const int i = tid & 127;                // local row 0..127
    int tj = (t_begin + j < NTT) ? t_begin + j : NTT - 1;
    int grow = tj * BRT + i;
    int rr = r[(grow < N_ROWS) ? grow : N_ROWS - 1];
    if (tid < TPB * KREL) sCnt[tid / KREL][tid % KREL] = 0;
    __syncthreads();
    int rank = atomicAdd(&sCnt[j][rr], 1);
    __syncthreads();
    if (tid < TPB) {
      int off = 0;
      #pragma unroll
      for (int k = 0; k < KREL; ++k) { int v = sCnt[tid][k]; sCnt[tid][k] = off; off += v; }
    }
    __syncthreads();
    int pos = sCnt[j][rr] + rank;
    sSrc[j][pos] = i;
    sRel[j][pos] = rr;
  }

  // ---- prologue B: stage ALL 5 relation weights -> bf16 LDS, swizzled ----
  {
    const float4* w4 = (const float4*)Wk;     // [5][64][128] f32 contiguous
    #pragma unroll
    for (int j = 0; j < 20; ++j) {
      int f4   = j * 512 + tid;               // 0..10239
      int k    = f4 >> 11;                    // 2048 float4 per relation
      int rowk = (f4 >> 5) & 63;
      int cc   = f4 & 31;
      int byte = (k << 14) + ((rowk * 256 + cc * 8) ^ ((rowk & 7) << 4));
      stbf4_pk(sW, byte, w4[f4]);
    }
  }
  if (tid < KREL * HDIM) sB[tid] = bk[tid];

  // layer-2 weights + biases in registers
  bf8_t wl[2][2];
  #pragma unroll
  for (int n2 = 0; n2 < 2; ++n2)
    #pragma unroll
    for (int k2 = 0; k2 < 2; ++k2) {
      const float* p = Wl + (size_t)(n2 * 16 + lrow) * HDIM + k2 * 32 + lkg * 8;
      wl[n2][k2] = cvt8(*(const float4*)p, *(const float4*)(p + 4));
    }
  const float blv0 = bl[lrow];
  const float blv1 = bl[16 + lrow];

  char* myX = (char*)sX + wid * 4096;   // this wave's private 16-slot region
  const int rowb_off = wid * 16;

  __syncthreads();   // sorts + sW + sB visible; LAST barrier in the kernel

  // prologue C: stage first tile's 16 sorted slots for this wave
  #pragma unroll
  for (int it = 0; it < 8; ++it) {
    int slot = rowb_off + it * 2 + sh;
    int grow = t_begin * BRT + sSrc[0][slot];
    grow = (grow < N_ROWS) ? grow : N_ROWS - 1;
    float4 a = *(const float4*)(X + (size_t)grow * FIN + c4 * 4);
    int rl   = it * 2 + sh;
    int byte = (rl * 256 + c4 * 8) ^ ((rl & 7) << 4);
    stbf4_pk(myX, byte, a);
  }

  for (int t = t_begin; t < t_end; ++t) {
    const int j = t - t_begin;
    const int tile0 = t * BRT;
    const bool do_stage = (t + 1 < t_end);

    // this lane's A-slot relation (sorted)
    const int myrel = sRel[j][rowb_off + lrow];

    // issue-early: loads of tile t+1's sorted slots (within-window gather)
    float4 ld[8];
    if (do_stage) {
      #pragma unroll
      for (int it = 0; it < 8; ++it) {
        int slot = rowb_off + it * 2 + sh;
        int grow = (t + 1) * BRT + sSrc[j + 1][slot];
        grow = (grow < N_ROWS) ? grow : N_ROWS - 1;
        ld[it] = *(const float4*)(X + (size_t)grow * FIN + c4 * 4);
      }
    }

    // epilogue inputs via sorted slots
    int lsrcQ[4], rQ[4]; float cQ[4];
    #pragma unroll
    for (int q = 0; q < 4; ++q) {
      int slot = rowb_off + lkg * 4 + q;
      int ls   = sSrc[j][slot];
      lsrcQ[q] = ls;
      rQ[q]    = sRel[j][slot];
      int rc   = tile0 + ls;
      cQ[q]    = c[(rc < N_ROWS) ? rc : N_ROWS - 1];
    }

    __builtin_amdgcn_sched_barrier(0);   // pin: loads above, compute below

    // layer 1: masked accumulation with wave-uniform relation skip, K = 128
    f32x4 acc[4];
    #pragma unroll
    for (int n = 0; n < 4; ++n) acc[n] = f32x4{0.f, 0.f, 0.f, 0.f};

    const bf8_t zero8 = {};
    const int axor = (lrow & 7) << 4;
    bf8_t au[4];
    #pragma unroll
    for (int kc = 0; kc < 4; ++kc) {
      const int kb = (kc * 32 + lkg * 8) * 2;
      au[kc] = lds_load16(myX, (lrow * 256 + kb) ^ axor);
    }
    #pragma unroll
    for (int k = 0; k < KREL; ++k) {
      if (__any(myrel == k)) {             // wave-uniform: sorted tiles skip ~3.5 of 5
        const int kofs = k << 14;
        #pragma unroll
        for (int kc = 0; kc < 4; ++kc) {
          const int kb = (kc * 32 + lkg * 8) * 2;
          bf8_t auk = (myrel == k) ? au[kc] : zero8;
          #pragma unroll
          for (int n = 0; n < 4; ++n) {
            int brow = n * 16 + lrow;
            int bx   = kofs + ((brow * 256 + kb) ^ ((brow & 7) << 4));
            acc[n] = __builtin_amdgcn_mfma_f32_16x16x32_bf16(auk, lds_load16(sW, bx), acc[n], 0, 0, 0);
          }
        }
      }
    }

    // epilogue 1: H = relu(c*(acc + b[rel])) -> bf16 into this wave's region
    #pragma unroll
    for (int n = 0; n < 4; ++n) {
      int hcol = n * 16 + lrow;
      #pragma unroll
      for (int q = 0; q < 4; ++q) {
        int rr   = lkg * 4 + q;      // local slot 0..15
        int byte = (rr * 128 + hcol * 2) ^ ((rr & 7) << 4);
        float bb = sB[rQ[q] * HDIM + hcol];
        float hv = fmaxf(cQ[q] * (acc[n][q] + bb), 0.f);
        *(unsigned short*)(myX + byte) = (unsigned short)(pk2(hv, hv) & 0xFFFFu);
      }
    }

    // layer 2: [16 slots] x [32 o], K = 64 (same-wave LDS RAW; no barrier)
    f32x4 acc2[2];
    acc2[0] = f32x4{0.f, 0.f, 0.f, 0.f};
    acc2[1] = f32x4{0.f, 0.f, 0.f, 0.f};
    #pragma unroll
    for (int k2 = 0; k2 < 2; ++k2) {
      const int kb = (k2 * 32 + lkg * 8) * 2;
      const int ax = (lrow * 128 + kb) ^ axor;
      bf8_t a2 = lds_load16(myX, ax);
      #pragma unroll
      for (int n2 = 0; n2 < 2; ++n2)
        acc2[n2] = __builtin_amdgcn_mfma_f32_16x16x32_bf16(a2, wl[n2][k2], acc2[n2], 0, 0, 0);
    }

    // epilogue 2: out = relu(acc2 + bl), stores scattered within the 128-row window
    const size_t obase = (size_t)side * N_ROWS * ODIM;
    #pragma unroll
    for (int n2 = 0; n2 < 2; ++n2) {
      int col  = n2 * 16 + lrow;
      float bb = (n2 == 0) ? blv0 : blv1;
      #pragma unroll
      for (int q = 0; q < 4; ++q) {
        int row = tile0 + lsrcQ[q];
        if (row < N_ROWS)
          out[obase + (size_t)row * ODIM + col] = fmaxf(acc2[n2][q] + bb, 0.f);
      }
    }

    __builtin_amdgcn_sched_barrier(0);   // pin: staged writes stay below compute

    // write-late: convert + ds_write tile t+1 into the SAME wave-private region
    if (do_stage) {
      #pragma unroll
      for (int it = 0; it < 8; ++it) {
        int rl   = it * 2 + sh;
        int byte = (rl * 256 + c4 * 8) ^ ((rl & 7) << 4);
        stbf4_pk(myX, byte, ld[it]);
      }
    }
  }
}

extern "C" void kernel_launch(void* const* d_in, const int* in_sizes, int n_in,
                              void* d_out, int out_size, void* d_ws, size_t ws_size,
                              hipStream_t stream) {
  const float* user = (const float*)d_in[0];
  const float* item = (const float*)d_in[1];
  const int*   r    = (const int*)d_in[2];
  const float* c    = (const float*)d_in[3];
  const float* Wu   = (const float*)d_in[4];
  const float* bu   = (const float*)d_in[5];
  const float* Wv   = (const float*)d_in[6];
  const float* bv   = (const float*)d_in[7];
  const float* Wl   = (const float*)d_in[8];
  const float* bl   = (const float*)d_in[9];
  float* out = (float*)d_out;

  gcn_main<<<2 * NCHUNK, 512, 0, stream>>>(user, item, r, c, Wu, bu, Wv, bv,
                                           Wl, bl, out);
}